// Round 1
// baseline (1368.638 us; speedup 1.0000x reference)
//
#include <hip/hip_runtime.h>

// Turkish-aware cross-entropy: mean over rows of
//   (logsumexp(pred[i]) - pred[i][target[i]]) * scale(argmax(pred[i]), target[i])
// scale = 0.8 if argmax-char and target-char fall in the same Turkish
// similar-chars group {i/ı, o/ö, u/ü, g/ğ}, else 1.0.
//
// N=524288, V=512. HBM-bound: 1.07 GB single pass over pred.

#define V 512

// group id per codepoint (0 = none). All group chars < 512.
__device__ __forceinline__ int grp(int c) {
    if (c == 105 || c == 305) return 1;  // i, ı
    if (c == 111 || c == 246) return 2;  // o, ö
    if (c == 117 || c == 252) return 3;  // u, ü
    if (c == 103 || c == 287) return 4;  // g, ğ
    return 0;
}

__global__ __launch_bounds__(256) void turkish_loss_kernel(
    const float* __restrict__ pred, const int* __restrict__ target,
    float* __restrict__ ws_sum, int N)
{
    __shared__ float wave_part[4];
    const int lane  = threadIdx.x & 63;
    const int wid   = threadIdx.x >> 6;          // wave id in block (0..3)
    const int gwave = blockIdx.x * 4 + wid;      // global wave id
    const int nwave = gridDim.x * 4;

    float acc = 0.0f;

    for (int row = gwave; row < N; row += nwave) {
        const float4* p = (const float4*)(pred + (size_t)row * V);
        // lane i: elements [4i, 4i+4) and [256+4i, 256+4i+4)
        float4 a = p[lane];
        float4 b = p[64 + lane];
        float v[8] = {a.x, a.y, a.z, a.w, b.x, b.y, b.z, b.w};
        const int base0 = 4 * lane;
        const int base1 = 256 + 4 * lane;

        // ---- local max + argmax (first occurrence on ties) ----
        float m = v[0]; int mi = base0;
        #pragma unroll
        for (int j = 1; j < 4; ++j)
            if (v[j] > m) { m = v[j]; mi = base0 + j; }
        #pragma unroll
        for (int j = 0; j < 4; ++j)
            if (v[4 + j] > m) { m = v[4 + j]; mi = base1 + j; }

        // ---- wave butterfly argmax (all lanes end with row max+idx) ----
        #pragma unroll
        for (int off = 1; off < 64; off <<= 1) {
            float m2 = __shfl_xor(m, off);
            int   i2 = __shfl_xor(mi, off);
            if (m2 > m || (m2 == m && i2 < mi)) { m = m2; mi = i2; }
        }

        // ---- sumexp + target logit ----
        const int t = target[row];
        float s = 0.0f, tv = 0.0f;
        #pragma unroll
        for (int j = 0; j < 4; ++j) {
            s += __expf(v[j] - m);
            tv += (base0 + j == t) ? v[j] : 0.0f;
        }
        #pragma unroll
        for (int j = 0; j < 4; ++j) {
            s += __expf(v[4 + j] - m);
            tv += (base1 + j == t) ? v[4 + j] : 0.0f;
        }
        #pragma unroll
        for (int off = 1; off < 64; off <<= 1) {
            s  += __shfl_xor(s, off);
            tv += __shfl_xor(tv, off);
        }

        // all lanes hold identical (m, mi, s, tv); lane 0 accumulates
        if (lane == 0) {
            float loss = m + __logf(s) - tv;
            int gp = grp(mi), gt = grp(t);
            float scale = (gp > 0 && gp == gt) ? 0.8f : 1.0f;
            acc += loss * scale;
        }
    }

    if (lane == 0) wave_part[wid] = acc;
    __syncthreads();
    if (threadIdx.x == 0) {
        float bsum = wave_part[0] + wave_part[1] + wave_part[2] + wave_part[3];
        atomicAdd(ws_sum, bsum);
    }
}

__global__ void turkish_loss_finalize(const float* __restrict__ ws_sum,
                                      float* __restrict__ out, float invN)
{
    out[0] = ws_sum[0] * invN;
}

extern "C" void kernel_launch(void* const* d_in, const int* in_sizes, int n_in,
                              void* d_out, int out_size, void* d_ws, size_t ws_size,
                              hipStream_t stream) {
    const float* pred   = (const float*)d_in[0];
    const int*   target = (const int*)d_in[1];
    const int N = in_sizes[1];          // 524288 rows
    float* ws_sum = (float*)d_ws;

    // harness re-poisons d_ws to 0xAA before every timed launch
    hipMemsetAsync(d_ws, 0, sizeof(float), stream);

    // 2048 blocks x 256 thr = 8192 waves (64 rows/wave), 8 blocks/CU
    turkish_loss_kernel<<<dim3(2048), dim3(256), 0, stream>>>(pred, target, ws_sum, N);
    turkish_loss_finalize<<<1, 1, 0, stream>>>(ws_sum, (float*)d_out, 1.0f / (float)N);
}